// Round 2
// baseline (443.859 us; speedup 1.0000x reference)
//
#include <hip/hip_runtime.h>
#include <math.h>

#define B_   8
#define P_   196
#define L_   80
#define DIM1 2048
#define DIM2 300
#define ATT  1024

// ---------------------------------------------------------------- fast tanh
// tanh(x) = 1 - 2/(exp(2x)+1).  exp via v_exp_f32 (2^t), rcp via v_rcp_f32.
// No overflow: exp->inf gives 1.0, exp->0 gives -1.0.
__device__ inline float fast_tanh(float x) {
    float t = __expf(2.0f * x);                 // e^{2x} (native v_exp path)
    float r = __builtin_amdgcn_rcpf(t + 1.0f);  // ~1 ulp approx reciprocal
    return fmaf(-2.0f, r, 1.0f);
}

// ---------------------------------------------------------------- prep: w = Wh@Wt, bias = bh.Wt + bt
// one wave per output row; wave ATT computes the scalar bias.
__global__ __launch_bounds__(256) void prep_w(const float* __restrict__ Wh,
                                              const float* __restrict__ bh,
                                              const float* __restrict__ Wt,
                                              const float* __restrict__ btp,
                                              float* __restrict__ w,
                                              float* __restrict__ biasp) {
    const int tid  = threadIdx.x;
    const int lane = tid & 63;
    const int row  = blockIdx.x * 4 + (tid >> 6);
    if (row < ATT) {
        const float* wr = Wh + (size_t)row * ATT;
        float acc = 0.0f;
#pragma unroll
        for (int it = 0; it < ATT / 256; ++it) {
            const int i = it * 256 + lane * 4;
            const float4 a = *reinterpret_cast<const float4*>(wr + i);
            const float4 b = *reinterpret_cast<const float4*>(Wt + i);
            acc = fmaf(a.x, b.x, acc);
            acc = fmaf(a.y, b.y, acc);
            acc = fmaf(a.z, b.z, acc);
            acc = fmaf(a.w, b.w, acc);
        }
#pragma unroll
        for (int o = 32; o >= 1; o >>= 1) acc += __shfl_xor(acc, o);
        if (lane == 0) w[row] = acc;
    } else if (row == ATT) {
        float acc = 0.0f;
#pragma unroll
        for (int it = 0; it < ATT / 256; ++it) {
            const int i = it * 256 + lane * 4;
            const float4 a = *reinterpret_cast<const float4*>(bh + i);
            const float4 b = *reinterpret_cast<const float4*>(Wt + i);
            acc = fmaf(a.x, b.x, acc);
            acc = fmaf(a.y, b.y, acc);
            acc = fmaf(a.z, b.z, acc);
            acc = fmaf(a.w, b.w, acc);
        }
#pragma unroll
        for (int o = 32; o >= 1; o >>= 1) acc += __shfl_xor(acc, o);
        if (lane == 0) biasp[0] = acc + btp[0];
    }
}

// ---------------------------------------------------------------- f32 tiled SGEMM
// C[M,N] = A[M,K] @ B[K,N], all row-major. 64x64 tile, BK=16, 256 threads,
// 4x4 micro-tile per thread. LDS rows padded to 68 floats (272 B, 16-aligned,
// 2-way-max bank aliasing which is free on CDNA4). Inner loop uses
// ds_read_b128 (float4) so it is FMA-issue-bound, not LDS-issue-bound.
#define BM 64
#define BN 64
#define BK 16
#define LDP 68

__global__ __launch_bounds__(256) void sgemm_f32(const float* __restrict__ A,
                                                 const float* __restrict__ Bm,
                                                 float* __restrict__ C,
                                                 int M, int N, int K) {
    __shared__ float As[BK][LDP];
    __shared__ float Bs[BK][LDP];
    const int tid = threadIdx.x;
    const int tx = tid & 15;
    const int ty = tid >> 4;
    const int m0 = blockIdx.y * BM;
    const int n0 = blockIdx.x * BN;

    const int am = tid >> 2;
    const int ak = (tid & 3) * 4;
    const int bk = tid >> 4;
    const int bn = (tid & 15) * 4;

    float acc[4][4] = {};

    for (int k0 = 0; k0 < K; k0 += BK) {
        // stage A (transposed to [k][m])
        {
            const int gm = m0 + am;
            float v[4];
#pragma unroll
            for (int j = 0; j < 4; ++j) {
                const int gk = k0 + ak + j;
                v[j] = (gm < M && gk < K) ? A[(size_t)gm * K + gk] : 0.0f;
            }
#pragma unroll
            for (int j = 0; j < 4; ++j) As[ak + j][am] = v[j];
        }
        // stage B ([k][n])
        {
            const int gk = k0 + bk;
#pragma unroll
            for (int j = 0; j < 4; ++j) {
                const int gn = n0 + bn + j;
                Bs[bk][bn + j] = (gk < K && gn < N) ? Bm[(size_t)gk * N + gn] : 0.0f;
            }
        }
        __syncthreads();
#pragma unroll
        for (int k = 0; k < BK; ++k) {
            const float4 a4 = *reinterpret_cast<const float4*>(&As[k][ty * 4]);
            const float4 b4 = *reinterpret_cast<const float4*>(&Bs[k][tx * 4]);
            const float a[4] = {a4.x, a4.y, a4.z, a4.w};
            const float b[4] = {b4.x, b4.y, b4.z, b4.w};
#pragma unroll
            for (int i = 0; i < 4; ++i)
#pragma unroll
                for (int j = 0; j < 4; ++j)
                    acc[i][j] = fmaf(a[i], b[j], acc[i][j]);
        }
        __syncthreads();
    }

#pragma unroll
    for (int i = 0; i < 4; ++i) {
        const int gm = m0 + ty * 4 + i;
        if (gm >= M) continue;
#pragma unroll
        for (int j = 0; j < 4; ++j) {
            const int gn = n0 + tx * 4 + j;
            if (gn < N) C[(size_t)gm * N + gn] = acc[i][j];
        }
    }
}

// ---------------------------------------------------------------- fused score + softmax
// One block per (b,l), mapped so batch b -> XCD b (blockIdx.x % 8 == b under
// round-robin dispatch): the 800 KB a1 slice for batch b stays L2-resident
// across its 80 blocks. a2 row + w staged in LDS; each wave owns p = wave,
// wave+4, ...; lane covers 16 a-elements via 4 float4 loads of a1.
__global__ __launch_bounds__(256) void score_softmax(const float* __restrict__ a1,
                                                     const float* __restrict__ a2,
                                                     const float* __restrict__ w,
                                                     const float* __restrict__ biasp,
                                                     float* __restrict__ alpha) {
    __shared__ float a2s[ATT];
    __shared__ float ws[ATT];
    __shared__ float sc[P_];
    __shared__ float red[4];
    const int tid  = threadIdx.x;
    const int lane = tid & 63;
    const int wave = tid >> 6;
    const int b = blockIdx.x & 7;      // batch -> XCD
    const int l = blockIdx.x >> 3;
    const float bias = biasp[0];

    const float* a2p = a2 + (size_t)(b * L_ + l) * ATT;
    for (int i = tid; i < ATT; i += 256) {
        a2s[i] = a2p[i];
        ws[i]  = w[i];
    }
    __syncthreads();

    for (int p = wave; p < P_; p += 4) {
        const float* a1p = a1 + (size_t)(b * P_ + p) * ATT;
        float acc = 0.0f;
#pragma unroll
        for (int it = 0; it < ATT / 256; ++it) {
            const int i = it * 256 + lane * 4;
            const float4 v = *reinterpret_cast<const float4*>(a1p + i);
            acc = fmaf(fast_tanh(v.x * a2s[i + 0]), ws[i + 0], acc);
            acc = fmaf(fast_tanh(v.y * a2s[i + 1]), ws[i + 1], acc);
            acc = fmaf(fast_tanh(v.z * a2s[i + 2]), ws[i + 2], acc);
            acc = fmaf(fast_tanh(v.w * a2s[i + 3]), ws[i + 3], acc);
        }
#pragma unroll
        for (int o = 32; o >= 1; o >>= 1) acc += __shfl_xor(acc, o);
        if (lane == 0) sc[p] = acc + bias;
    }
    __syncthreads();

    // softmax over the 196 scores (threads 196..255 idle with -inf/0)
    const float v = (tid < P_) ? sc[tid] : -INFINITY;
    float m = v;
#pragma unroll
    for (int o = 32; o >= 1; o >>= 1) m = fmaxf(m, __shfl_xor(m, o));
    if (lane == 0) red[wave] = m;
    __syncthreads();
    m = fmaxf(fmaxf(red[0], red[1]), fmaxf(red[2], red[3]));

    const float e = (tid < P_) ? __expf(v - m) : 0.0f;
    float s = e;
#pragma unroll
    for (int o = 32; o >= 1; o >>= 1) s += __shfl_xor(s, o);
    __syncthreads();
    if (lane == 0) red[wave] = s;
    __syncthreads();
    s = red[0] + red[1] + red[2] + red[3];

    if (tid < P_) alpha[(size_t)(b * L_ + l) * P_ + tid] = e / s;
}

// ---------------------------------------------------------------- label_repr = alpha @ x1 (per batch)
// Block: (b, 4 l-rows, 512 d-cols). alpha staged transposed [p][4] so the
// inner loop is one broadcast float4 LDS read + one float2 x1 read + 8 FMA.
#define LT 4
#define DT 512
__global__ __launch_bounds__(256) void label_kernel(const float* __restrict__ alpha,
                                                    const float* __restrict__ x1,
                                                    float* __restrict__ out) {
    __shared__ float al[P_][LT];
    const int tid = threadIdx.x;
    const int b  = blockIdx.z;
    const int l0 = blockIdx.y * LT;
    const int d0 = blockIdx.x * DT;

    for (int idx = tid; idx < P_ * LT; idx += 256) {
        const int p = idx >> 2;
        const int l = idx & 3;
        al[p][l] = alpha[((size_t)(b * L_ + l0 + l)) * P_ + p];
    }
    __syncthreads();

    const int d = d0 + tid * 2;
    float acc[LT][2] = {};
    for (int p = 0; p < P_; ++p) {
        const float2 x = *reinterpret_cast<const float2*>(x1 + ((size_t)(b * P_ + p)) * DIM1 + d);
        const float4 a4 = *reinterpret_cast<const float4*>(&al[p][0]);
        acc[0][0] = fmaf(a4.x, x.x, acc[0][0]);
        acc[0][1] = fmaf(a4.x, x.y, acc[0][1]);
        acc[1][0] = fmaf(a4.y, x.x, acc[1][0]);
        acc[1][1] = fmaf(a4.y, x.y, acc[1][1]);
        acc[2][0] = fmaf(a4.z, x.x, acc[2][0]);
        acc[2][1] = fmaf(a4.z, x.y, acc[2][1]);
        acc[3][0] = fmaf(a4.w, x.x, acc[3][0]);
        acc[3][1] = fmaf(a4.w, x.y, acc[3][1]);
    }
#pragma unroll
    for (int l = 0; l < LT; ++l) {
        float* op = out + ((size_t)(b * L_ + l0 + l)) * DIM1 + d;
        op[0] = acc[l][0];
        op[1] = acc[l][1];
    }
}

// ---------------------------------------------------------------- launch
extern "C" void kernel_launch(void* const* d_in, const int* in_sizes, int n_in,
                              void* d_out, int out_size, void* d_ws, size_t ws_size,
                              hipStream_t stream) {
    const float* x1 = (const float*)d_in[0];
    const float* x2 = (const float*)d_in[1];
    const float* W1 = (const float*)d_in[2];
    const float* W2 = (const float*)d_in[3];
    const float* Wh = (const float*)d_in[4];
    const float* bh = (const float*)d_in[5];
    const float* Wt = (const float*)d_in[6];
    const float* bt = (const float*)d_in[7];

    float* out       = (float*)d_out;
    float* label_out = out;                                  // B*L*DIM1
    float* alpha_out = out + (size_t)B_ * L_ * DIM1;         // B*L*P

    float* ws    = (float*)d_ws;
    float* a1    = ws;                                       // 1568*1024
    float* a2    = a1 + (size_t)B_ * P_ * ATT;               // 640*1024
    float* wv    = a2 + (size_t)B_ * L_ * ATT;               // 1024
    float* biasv = wv + ATT;                                 // 1

    prep_w<<<ATT / 4 + 1, 256, 0, stream>>>(Wh, bh, Wt, bt, wv, biasv);

    sgemm_f32<<<dim3(ATT / BN, (B_ * P_ + BM - 1) / BM), 256, 0, stream>>>(
        x1, W1, a1, B_ * P_, ATT, DIM1);
    sgemm_f32<<<dim3(ATT / BN, (B_ * L_ + BM - 1) / BM), 256, 0, stream>>>(
        x2, W2, a2, B_ * L_, ATT, DIM2);

    score_softmax<<<B_ * L_, 256, 0, stream>>>(a1, a2, wv, biasv, alpha_out);

    label_kernel<<<dim3(DIM1 / DT, L_ / LT, B_), 256, 0, stream>>>(
        alpha_out, x1, label_out);
}

// Round 3
// 248.216 us; speedup vs baseline: 1.7882x; 1.7882x over previous
//
#include <hip/hip_runtime.h>
#include <math.h>

#define B_   8
#define P_   196
#define L_   80
#define DIM1 2048
#define DIM2 300
#define ATT  1024

typedef __attribute__((ext_vector_type(8))) short short8_t;
typedef __attribute__((ext_vector_type(4))) float f32x4_t;

__device__ inline unsigned short f2bf(float f) {
    unsigned int u = __float_as_uint(f);
    u += 0x7fff + ((u >> 16) & 1);          // RNE
    return (unsigned short)(u >> 16);
}
__device__ inline float bf2f(unsigned short h) {
    return __uint_as_float(((unsigned int)h) << 16);
}

// ---------------------------------------------------------------- prep: w = Wh@Wt, bias = bh.Wt + bt
__global__ __launch_bounds__(256) void prep_w(const float* __restrict__ Wh,
                                              const float* __restrict__ bh,
                                              const float* __restrict__ Wt,
                                              const float* __restrict__ btp,
                                              float* __restrict__ w,
                                              float* __restrict__ biasp) {
    const int tid  = threadIdx.x;
    const int lane = tid & 63;
    const int row  = blockIdx.x * 4 + (tid >> 6);
    const float* src = (row < ATT) ? (Wh + (size_t)row * ATT) : bh;
    if (row <= ATT) {
        float acc = 0.0f;
#pragma unroll
        for (int it = 0; it < ATT / 256; ++it) {
            const int i = it * 256 + lane * 4;
            const float4 a = *reinterpret_cast<const float4*>(src + i);
            const float4 b = *reinterpret_cast<const float4*>(Wt + i);
            acc = fmaf(a.x, b.x, acc);
            acc = fmaf(a.y, b.y, acc);
            acc = fmaf(a.z, b.z, acc);
            acc = fmaf(a.w, b.w, acc);
        }
#pragma unroll
        for (int o = 32; o >= 1; o >>= 1) acc += __shfl_xor(acc, o);
        if (lane == 0) {
            if (row < ATT) w[row] = acc;
            else           biasp[0] = acc + btp[0];
        }
    }
}

// bias2 = bias + sum(w)   (score = bias + sumw - 2*sum(w*r))
__global__ __launch_bounds__(256) void prep_sum(const float* __restrict__ w,
                                                float* __restrict__ biasp) {
    __shared__ float red[4];
    const int tid = threadIdx.x;
    float s = 0.f;
    for (int i = tid; i < ATT; i += 256) s += w[i];
#pragma unroll
    for (int o = 32; o >= 1; o >>= 1) s += __shfl_xor(s, o);
    if ((tid & 63) == 0) red[tid >> 6] = s;
    __syncthreads();
    if (tid == 0) biasp[1] = biasp[0] + red[0] + red[1] + red[2] + red[3];
}

// ---------------------------------------------------------------- transpose+cast: in[Ksrc][1024] f32 -> out[1024][Kpad] bf16 (zero-pad k)
__global__ __launch_bounds__(256) void tcast(const float* __restrict__ in,
                                             unsigned short* __restrict__ out,
                                             int Ksrc, int Kpad) {
    __shared__ unsigned short tile[32][34];
    const int tx = threadIdx.x & 31, ty = threadIdx.x >> 5;   // 32 x 8
    const int k0 = blockIdx.x * 32, n0 = blockIdx.y * 32;
#pragma unroll
    for (int i = 0; i < 4; ++i) {
        const int r = k0 + ty + i * 8;
        const float v = (r < Ksrc) ? in[(size_t)r * 1024 + n0 + tx] : 0.f;
        tile[ty + i * 8][tx] = f2bf(v);
    }
    __syncthreads();
#pragma unroll
    for (int i = 0; i < 4; ++i) {
        const int n = ty + i * 8;
        out[(size_t)(n0 + n) * Kpad + k0 + tx] = tile[tx][n];
    }
}

// ---------------------------------------------------------------- bf16 MFMA GEMM
// C[M][1024](bf16) = A[M][Ksrc](f32, cast on stage) @ B^T  with B given
// transposed as Bt[1024][Kpad](bf16). 128x128 tile, BK=32, 4 waves (64x64 each),
// 16x16x32 bf16 MFMA. LDS [row][k] bf16 with XOR swizzle byte^=((row&7)<<4):
// conflict-free on both b128 stage-writes and b128 fragment reads.
__global__ __launch_bounds__(256) void gemm_bf16(const float* __restrict__ Af,
                                                 const unsigned short* __restrict__ Bt,
                                                 unsigned short* __restrict__ C,
                                                 int M, int Ksrc, int Kpad) {
    __shared__ __align__(16) char smem[16384];
    char* smA = smem;
    char* smB = smem + 8192;
    const int tid  = threadIdx.x;
    const int lane = tid & 63;
    const int wave = tid >> 6;
    const int wm = (wave >> 1) * 64;
    const int wn = (wave & 1) * 64;
    const int m0 = blockIdx.y * 128;
    const int n0 = blockIdx.x * 128;

    const int sm  = tid >> 2;          // stage row (0..63, +64 second half)
    const int sk8 = (tid & 3) * 8;     // k element offset 0,8,16,24

    f32x4_t acc[4][4] = {};

    for (int k0 = 0; k0 < Kpad; k0 += 32) {
        const bool fullk = (k0 + 32 <= Ksrc);
#pragma unroll
        for (int half = 0; half < 2; ++half) {
            const int row = sm + half * 64;
            const int st  = (row * 64 + sk8 * 2) ^ ((row & 7) << 4);
            // A: f32 -> bf16 on the fly
            {
                const int gm = m0 + row;
                float vf[8];
                if (gm < M && fullk) {
                    const float4 u0 = *reinterpret_cast<const float4*>(Af + (size_t)gm * Ksrc + k0 + sk8);
                    const float4 u1 = *reinterpret_cast<const float4*>(Af + (size_t)gm * Ksrc + k0 + sk8 + 4);
                    vf[0] = u0.x; vf[1] = u0.y; vf[2] = u0.z; vf[3] = u0.w;
                    vf[4] = u1.x; vf[5] = u1.y; vf[6] = u1.z; vf[7] = u1.w;
                } else if (gm < M) {
#pragma unroll
                    for (int j = 0; j < 8; ++j) {
                        const int k = k0 + sk8 + j;
                        vf[j] = (k < Ksrc) ? Af[(size_t)gm * Ksrc + k] : 0.f;
                    }
                } else {
#pragma unroll
                    for (int j = 0; j < 8; ++j) vf[j] = 0.f;
                }
                short8_t h;
#pragma unroll
                for (int j = 0; j < 8; ++j) h[j] = (short)f2bf(vf[j]);
                *reinterpret_cast<short8_t*>(smA + st) = h;
            }
            // B: already bf16 [n][Kpad], zero-padded in k
            {
                const short8_t vb = *reinterpret_cast<const short8_t*>(
                    Bt + (size_t)(n0 + row) * Kpad + k0 + sk8);
                *reinterpret_cast<short8_t*>(smB + st) = vb;
            }
        }
        __syncthreads();

        short8_t af[4], bfr[4];
#pragma unroll
        for (int i = 0; i < 4; ++i) {
            const int r  = wm + i * 16 + (lane & 15);
            const int ad = (r * 64 + ((lane >> 4) << 4)) ^ ((r & 7) << 4);
            af[i] = *reinterpret_cast<const short8_t*>(smA + ad);
        }
#pragma unroll
        for (int j = 0; j < 4; ++j) {
            const int r  = wn + j * 16 + (lane & 15);
            const int ad = (r * 64 + ((lane >> 4) << 4)) ^ ((r & 7) << 4);
            bfr[j] = *reinterpret_cast<const short8_t*>(smB + ad);
        }
#pragma unroll
        for (int i = 0; i < 4; ++i)
#pragma unroll
            for (int j = 0; j < 4; ++j)
                acc[i][j] = __builtin_amdgcn_mfma_f32_16x16x32_bf16(af[i], bfr[j], acc[i][j], 0, 0, 0);
        __syncthreads();
    }

    // epilogue: C/D layout col=lane&15, row=(lane>>4)*4+q
#pragma unroll
    for (int i = 0; i < 4; ++i) {
        const int gmb = m0 + wm + i * 16 + ((lane >> 4) << 2);
#pragma unroll
        for (int j = 0; j < 4; ++j) {
            const int gn = n0 + wn + j * 16 + (lane & 15);
#pragma unroll
            for (int q = 0; q < 4; ++q) {
                const int gm = gmb + q;
                if (gm < M) C[(size_t)gm * 1024 + gn] = f2bf(acc[i][j][q]);
            }
        }
    }
}

// ---------------------------------------------------------------- fused score + softmax (bf16 a1/a2)
// score = bias2 - 2 * sum_a w[a] * rcp(exp2(C * a1 * a2) + 1),  C = 2*log2(e)
// aw[] LDS holds {a2*C, w} phi-permuted so the per-j ds_read_b64 is
// conflict-free while a1 stays short8-vectorized.
__global__ __launch_bounds__(256) void score_softmax(const unsigned short* __restrict__ a1b,
                                                     const unsigned short* __restrict__ a2b,
                                                     const float* __restrict__ w,
                                                     const float* __restrict__ biasp,
                                                     float* __restrict__ alpha) {
    __shared__ float2 aw[ATT];
    __shared__ float sc[P_];
    __shared__ float red[4];
    const int tid  = threadIdx.x;
    const int lane = tid & 63;
    const int wave = tid >> 6;
    const int b = blockIdx.x & 7;      // batch -> XCD (L2 residency of a1 slice)
    const int l = blockIdx.x >> 3;
    const float bias2 = biasp[1];

    const unsigned short* a2p = a2b + (size_t)(b * L_ + l) * ATT;
    for (int i = tid; i < ATT; i += 256) {
        const float a2v = bf2f(a2p[i]);
        const int li = i & 511;
        const int phi = (i & ~511) | (((li & 7) << 6) + (li >> 3));
        aw[phi] = make_float2(a2v * 2.885390082f, w[i]);   // 2*log2(e)
    }
    __syncthreads();

    for (int p = wave; p < P_; p += 4) {
        const unsigned short* a1p = a1b + (size_t)(b * P_ + p) * ATT;
        float acc = 0.0f;
#pragma unroll
        for (int it = 0; it < 2; ++it) {
            const short8_t v = *reinterpret_cast<const short8_t*>(a1p + it * 512 + lane * 8);
#pragma unroll
            for (int j = 0; j < 8; ++j) {
                const float f = bf2f((unsigned short)v[j]);
                const float2 c = aw[it * 512 + j * 64 + lane];
                const float e = __builtin_amdgcn_exp2f(f * c.x);
                const float r = __builtin_amdgcn_rcpf(e + 1.0f);
                acc = fmaf(c.y, r, acc);
            }
        }
#pragma unroll
        for (int o = 32; o >= 1; o >>= 1) acc += __shfl_xor(acc, o);
        if (lane == 0) sc[p] = bias2 - 2.0f * acc;
    }
    __syncthreads();

    const float v = (tid < P_) ? sc[tid] : -INFINITY;
    float m = v;
#pragma unroll
    for (int o = 32; o >= 1; o >>= 1) m = fmaxf(m, __shfl_xor(m, o));
    if (lane == 0) red[wave] = m;
    __syncthreads();
    m = fmaxf(fmaxf(red[0], red[1]), fmaxf(red[2], red[3]));

    const float e = (tid < P_) ? __expf(v - m) : 0.0f;
    float s = e;
#pragma unroll
    for (int o = 32; o >= 1; o >>= 1) s += __shfl_xor(s, o);
    __syncthreads();
    if (lane == 0) red[wave] = s;
    __syncthreads();
    s = red[0] + red[1] + red[2] + red[3];

    if (tid < P_) alpha[(size_t)(b * L_ + l) * P_ + tid] = e / s;
}

// ---------------------------------------------------------------- label_repr = alpha @ x1 (per batch)
#define LT 4
#define DT 512
__global__ __launch_bounds__(256) void label_kernel(const float* __restrict__ alpha,
                                                    const float* __restrict__ x1,
                                                    float* __restrict__ out) {
    __shared__ float al[P_][LT];
    const int tid = threadIdx.x;
    const int b  = blockIdx.z;
    const int l0 = blockIdx.y * LT;
    const int d0 = blockIdx.x * DT;

    for (int idx = tid; idx < P_ * LT; idx += 256) {
        const int p = idx >> 2;
        const int l = idx & 3;
        al[p][l] = alpha[((size_t)(b * L_ + l0 + l)) * P_ + p];
    }
    __syncthreads();

    const int d = d0 + tid * 2;
    float acc[LT][2] = {};
    for (int p = 0; p < P_; ++p) {
        const float2 x = *reinterpret_cast<const float2*>(x1 + ((size_t)(b * P_ + p)) * DIM1 + d);
        const float4 a4 = *reinterpret_cast<const float4*>(&al[p][0]);
        acc[0][0] = fmaf(a4.x, x.x, acc[0][0]);
        acc[0][1] = fmaf(a4.x, x.y, acc[0][1]);
        acc[1][0] = fmaf(a4.y, x.x, acc[1][0]);
        acc[1][1] = fmaf(a4.y, x.y, acc[1][1]);
        acc[2][0] = fmaf(a4.z, x.x, acc[2][0]);
        acc[2][1] = fmaf(a4.z, x.y, acc[2][1]);
        acc[3][0] = fmaf(a4.w, x.x, acc[3][0]);
        acc[3][1] = fmaf(a4.w, x.y, acc[3][1]);
    }
#pragma unroll
    for (int l = 0; l < LT; ++l) {
        float* op = out + ((size_t)(b * L_ + l0 + l)) * DIM1 + d;
        op[0] = acc[l][0];
        op[1] = acc[l][1];
    }
}

// ---------------------------------------------------------------- launch
extern "C" void kernel_launch(void* const* d_in, const int* in_sizes, int n_in,
                              void* d_out, int out_size, void* d_ws, size_t ws_size,
                              hipStream_t stream) {
    const float* x1 = (const float*)d_in[0];
    const float* x2 = (const float*)d_in[1];
    const float* W1 = (const float*)d_in[2];
    const float* W2 = (const float*)d_in[3];
    const float* Wh = (const float*)d_in[4];
    const float* bh = (const float*)d_in[5];
    const float* Wt = (const float*)d_in[6];
    const float* bt = (const float*)d_in[7];

    float* out       = (float*)d_out;
    float* label_out = out;                                  // B*L*DIM1
    float* alpha_out = out + (size_t)B_ * L_ * DIM1;         // B*L*P

    // workspace layout (ushort offsets); a2b aliases W1T (dead after a1 gemm)
    unsigned short* usw = (unsigned short*)d_ws;
    unsigned short* W1T = usw;                         // 1024*2048 = 2097152
    unsigned short* a2b = usw;                         // 640*1024  (aliases W1T)
    unsigned short* W2T = usw + 2097152;               // 1024*320  = 327680
    unsigned short* a1b = usw + 2424832;               // 1568*1024 = 1605632
    float* wv    = (float*)(usw + 4030464);            // 1024
    float* biasv = wv + ATT;                           // 2

    prep_w<<<ATT / 4 + 1, 256, 0, stream>>>(Wh, bh, Wt, bt, wv, biasv);
    prep_sum<<<1, 256, 0, stream>>>(wv, biasv);

    tcast<<<dim3(DIM1 / 32, 32), 256, 0, stream>>>(W1, W1T, DIM1, DIM1);
    tcast<<<dim3(320 / 32, 32), 256, 0, stream>>>(W2, W2T, DIM2, 320);

    gemm_bf16<<<dim3(8, 13), 256, 0, stream>>>(x1, W1T, a1b, B_ * P_, DIM1, DIM1);
    gemm_bf16<<<dim3(8, 5), 256, 0, stream>>>(x2, W2T, a2b, B_ * L_, DIM2, 320);

    score_softmax<<<B_ * L_, 256, 0, stream>>>(a1b, a2b, wv, biasv, alpha_out);

    label_kernel<<<dim3(DIM1 / DT, L_ / LT, B_), 256, 0, stream>>>(
        alpha_out, x1, label_out);
}

// Round 5
// 196.003 us; speedup vs baseline: 2.2645x; 1.2664x over previous
//
#include <hip/hip_runtime.h>
#include <math.h>

#define B_   8
#define P_   196
#define L_   80
#define DIM1 2048
#define DIM2 300
#define ATT  1024

typedef __attribute__((ext_vector_type(8))) short short8_t;
typedef __attribute__((ext_vector_type(4))) float f32x4_t;

__device__ inline unsigned short f2bf(float f) {
    unsigned int u = __float_as_uint(f);
    u += 0x7fff + ((u >> 16) & 1);          // RNE
    return (unsigned short)(u >> 16);
}
__device__ inline float bf2f(unsigned short h) {
    return __uint_as_float(((unsigned int)h) << 16);
}

// ---------------------------------------------------------------- prep: w = Wh@Wt, bias = bh.Wt + bt
__global__ __launch_bounds__(256) void prep_w(const float* __restrict__ Wh,
                                              const float* __restrict__ bh,
                                              const float* __restrict__ Wt,
                                              const float* __restrict__ btp,
                                              float* __restrict__ w,
                                              float* __restrict__ biasp) {
    const int tid  = threadIdx.x;
    const int lane = tid & 63;
    const int row  = blockIdx.x * 4 + (tid >> 6);
    const float* src = (row < ATT) ? (Wh + (size_t)row * ATT) : bh;
    if (row <= ATT) {
        float acc = 0.0f;
#pragma unroll
        for (int it = 0; it < ATT / 256; ++it) {
            const int i = it * 256 + lane * 4;
            const float4 a = *reinterpret_cast<const float4*>(src + i);
            const float4 b = *reinterpret_cast<const float4*>(Wt + i);
            acc = fmaf(a.x, b.x, acc);
            acc = fmaf(a.y, b.y, acc);
            acc = fmaf(a.z, b.z, acc);
            acc = fmaf(a.w, b.w, acc);
        }
#pragma unroll
        for (int o = 32; o >= 1; o >>= 1) acc += __shfl_xor(acc, o);
        if (lane == 0) {
            if (row < ATT) w[row] = acc;
            else           biasp[0] = acc + btp[0];
        }
    }
}

// bias2 = bias + sum(w)   (score = bias + sumw - 2*sum(w*r))
__global__ __launch_bounds__(256) void prep_sum(const float* __restrict__ w,
                                                float* __restrict__ biasp) {
    __shared__ float red[4];
    const int tid = threadIdx.x;
    float s = 0.f;
    for (int i = tid; i < ATT; i += 256) s += w[i];
#pragma unroll
    for (int o = 32; o >= 1; o >>= 1) s += __shfl_xor(s, o);
    if ((tid & 63) == 0) red[tid >> 6] = s;
    __syncthreads();
    if (tid == 0) biasp[1] = biasp[0] + red[0] + red[1] + red[2] + red[3];
}

// ---------------------------------------------------------------- transpose+cast: in[Ksrc][1024] f32 -> out[1024][Kpad] bf16 (zero-pad k)
__global__ __launch_bounds__(256) void tcast(const float* __restrict__ in,
                                             unsigned short* __restrict__ out,
                                             int Ksrc, int Kpad) {
    __shared__ unsigned short tile[32][34];
    const int tx = threadIdx.x & 31, ty = threadIdx.x >> 5;   // 32 x 8
    const int k0 = blockIdx.x * 32, n0 = blockIdx.y * 32;
#pragma unroll
    for (int i = 0; i < 4; ++i) {
        const int r = k0 + ty + i * 8;
        const float v = (r < Ksrc) ? in[(size_t)r * 1024 + n0 + tx] : 0.f;
        tile[ty + i * 8][tx] = f2bf(v);
    }
    __syncthreads();
#pragma unroll
    for (int i = 0; i < 4; ++i) {
        const int n = ty + i * 8;
        out[(size_t)(n0 + n) * Kpad + k0 + tx] = tile[tx][n];
    }
}

// ---------------------------------------------------------------- bf16 MFMA GEMM, pipelined
// C[M][1024](bf16) = A[M][KSRC](f32, cast on stage) @ Bt[1024][KPAD](bf16)^T.
// 64x64 tile, BK=64, 4 waves (32x32 each), 16x16x32 bf16 MFMA.
// Double-buffered LDS (2 x (A 8KB + B 8KB)), ONE barrier per K-step:
//   iter t: ds_write tile t (regs) -> barrier -> issue global loads t+1
//           -> ds_read frags t + 8 MFMA.
// Loads for t+1 drain (vmcnt) at iter t+1's ds_write, hidden under compute t.
// LDS rows 128 B pitch, XOR swizzle byte^=((row&7)<<4): both ds_write_b128
// and ds_read_b128 are <=2-way (free) on 32 banks.
template<int KSRC, int KPAD>
__global__ __launch_bounds__(256) void gemm_bf16(const float* __restrict__ Af,
                                                 const unsigned short* __restrict__ Bt,
                                                 unsigned short* __restrict__ C,
                                                 int M) {
    constexpr int NT = KPAD / 64;
    __shared__ __align__(16) char smem[32768];   // [buf][A 8K | B 8K]
    const int tid  = threadIdx.x;
    const int lane = tid & 63;
    const int wave = tid >> 6;
    const int wm = (wave >> 1) * 32;
    const int wn = (wave & 1) * 32;
    const int m0 = blockIdx.y * 64;
    const int n0 = blockIdx.x * 64;

    const int row = tid >> 2;            // 0..63 staging row
    const int kc  = (tid & 3) * 16;      // k element offset within BK
    const int swz = (row & 7) << 4;
    const int sb  = row * 128 + kc * 2;  // staging byte base (pre-XOR)
    const int gm  = m0 + row;

    float4   ra[4];                      // 16 f32 of A
    short8_t rb[2];                      // 16 bf16 of B

    auto LOAD = [&](int t) {
        const int k0 = t * 64;
        if (gm < M && k0 + 64 <= KSRC) {
            const float* ap = Af + (size_t)gm * KSRC + k0 + kc;
            ra[0] = *reinterpret_cast<const float4*>(ap);
            ra[1] = *reinterpret_cast<const float4*>(ap + 4);
            ra[2] = *reinterpret_cast<const float4*>(ap + 8);
            ra[3] = *reinterpret_cast<const float4*>(ap + 12);
        } else {
            float* rf = reinterpret_cast<float*>(ra);
#pragma unroll
            for (int j = 0; j < 16; ++j) {
                const int k = k0 + kc + j;
                rf[j] = (gm < M && k < KSRC) ? Af[(size_t)gm * KSRC + k] : 0.f;
            }
        }
        const unsigned short* bp = Bt + (size_t)(n0 + row) * KPAD + k0 + kc;
        rb[0] = *reinterpret_cast<const short8_t*>(bp);
        rb[1] = *reinterpret_cast<const short8_t*>(bp + 8);
    };

    auto WRITE = [&](int buf) {
        char* smA = smem + buf * 16384;
        char* smB = smA + 8192;
        const float* rf = reinterpret_cast<const float*>(ra);
        short8_t h0, h1;
#pragma unroll
        for (int j = 0; j < 8; ++j) h0[j] = (short)f2bf(rf[j]);
#pragma unroll
        for (int j = 0; j < 8; ++j) h1[j] = (short)f2bf(rf[8 + j]);
        *reinterpret_cast<short8_t*>(smA + ((sb)      ^ swz)) = h0;
        *reinterpret_cast<short8_t*>(smA + ((sb + 16) ^ swz)) = h1;
        *reinterpret_cast<short8_t*>(smB + ((sb)      ^ swz)) = rb[0];
        *reinterpret_cast<short8_t*>(smB + ((sb + 16) ^ swz)) = rb[1];
    };

    f32x4_t acc[2][2] = {};
    const int fr_col = (lane >> 4) << 4;   // frag k-group byte offset
    const int fl     = lane & 15;

    LOAD(0);
#pragma unroll 2
    for (int t = 0; t < NT; ++t) {
        const int buf = t & 1;
        WRITE(buf);                        // vmcnt drain for tile t happens here
        __syncthreads();
        if (t + 1 < NT) LOAD(t + 1);       // issue next tile, no wait
        const char* smA = smem + buf * 16384;
        const char* smB = smA + 8192;
#pragma unroll
        for (int kk = 0; kk < 2; ++kk) {
            short8_t af[2], bf[2];
#pragma unroll
            for (int i = 0; i < 2; ++i) {
                const int r = wm + i * 16 + fl;
                af[i] = *reinterpret_cast<const short8_t*>(
                    smA + ((r * 128 + kk * 64 + fr_col) ^ ((r & 7) << 4)));
            }
#pragma unroll
            for (int j = 0; j < 2; ++j) {
                const int r = wn + j * 16 + fl;
                bf[j] = *reinterpret_cast<const short8_t*>(
                    smB + ((r * 128 + kk * 64 + fr_col) ^ ((r & 7) << 4)));
            }
#pragma unroll
            for (int i = 0; i < 2; ++i)
#pragma unroll
                for (int j = 0; j < 2; ++j)
                    acc[i][j] = __builtin_amdgcn_mfma_f32_16x16x32_bf16(af[i], bf[j], acc[i][j], 0, 0, 0);
        }
        __syncthreads();
    }

    // epilogue: C/D layout col=lane&15, row=(lane>>4)*4+q
#pragma unroll
    for (int i = 0; i < 2; ++i) {
        const int gmb = m0 + wm + i * 16 + ((lane >> 4) << 2);
#pragma unroll
        for (int j = 0; j < 2; ++j) {
            const int gn = n0 + wn + j * 16 + fl;
#pragma unroll
            for (int q = 0; q < 4; ++q) {
                const int gmq = gmb + q;
                if (gmq < M) C[(size_t)gmq * 1024 + gn] = f2bf(acc[i][j][q]);
            }
        }
    }
}

// ---------------------------------------------------------------- fused score + softmax (bf16 a1/a2)
// score = bias2 - 2 * sum_a w[a] * rcp(exp2(C * a1 * a2) + 1),  C = 2*log2(e)
__global__ __launch_bounds__(256) void score_softmax(const unsigned short* __restrict__ a1b,
                                                     const unsigned short* __restrict__ a2b,
                                                     const float* __restrict__ w,
                                                     const float* __restrict__ biasp,
                                                     float* __restrict__ alpha) {
    __shared__ float2 aw[ATT];
    __shared__ float sc[P_];
    __shared__ float red[4];
    const int tid  = threadIdx.x;
    const int lane = tid & 63;
    const int wave = tid >> 6;
    const int b = blockIdx.x & 7;      // batch -> XCD (L2 residency of a1 slice)
    const int l = blockIdx.x >> 3;
    const float bias2 = biasp[1];

    const unsigned short* a2p = a2b + (size_t)(b * L_ + l) * ATT;
    for (int i = tid; i < ATT; i += 256) {
        const float a2v = bf2f(a2p[i]);
        const int li = i & 511;
        const int phi = (i & ~511) | (((li & 7) << 6) + (li >> 3));
        aw[phi] = make_float2(a2v * 2.885390082f, w[i]);   // 2*log2(e)
    }
    __syncthreads();

    for (int p = wave; p < P_; p += 4) {
        const unsigned short* a1p = a1b + (size_t)(b * P_ + p) * ATT;
        float acc = 0.0f;
#pragma unroll
        for (int it = 0; it < 2; ++it) {
            const short8_t v = *reinterpret_cast<const short8_t*>(a1p + it * 512 + lane * 8);
#pragma unroll
            for (int j = 0; j < 8; ++j) {
                const float f = bf2f((unsigned short)v[j]);
                const float2 c = aw[it * 512 + j * 64 + lane];
                const float e = __builtin_amdgcn_exp2f(f * c.x);
                const float r = __builtin_amdgcn_rcpf(e + 1.0f);
                acc = fmaf(c.y, r, acc);
            }
        }
#pragma unroll
        for (int o = 32; o >= 1; o >>= 1) acc += __shfl_xor(acc, o);
        if (lane == 0) sc[p] = bias2 - 2.0f * acc;
    }
    __syncthreads();

    const float v = (tid < P_) ? sc[tid] : -INFINITY;
    float m = v;
#pragma unroll
    for (int o = 32; o >= 1; o >>= 1) m = fmaxf(m, __shfl_xor(m, o));
    if (lane == 0) red[wave] = m;
    __syncthreads();
    m = fmaxf(fmaxf(red[0], red[1]), fmaxf(red[2], red[3]));

    const float e = (tid < P_) ? __expf(v - m) : 0.0f;
    float s = e;
#pragma unroll
    for (int o = 32; o >= 1; o >>= 1) s += __shfl_xor(s, o);
    __syncthreads();
    if (lane == 0) red[wave] = s;
    __syncthreads();
    s = red[0] + red[1] + red[2] + red[3];

    if (tid < P_) alpha[(size_t)(b * L_ + l) * P_ + tid] = e / s;
}

// ---------------------------------------------------------------- label_repr = alpha @ x1 (per batch)
#define LT 4
#define DT 512
__global__ __launch_bounds__(256) void label_kernel(const float* __restrict__ alpha,
                                                    const float* __restrict__ x1,
                                                    float* __restrict__ out) {
    __shared__ float al[P_][LT];
    const int tid = threadIdx.x;
    const int b  = blockIdx.z;
    const int l0 = blockIdx.y * LT;
    const int d0 = blockIdx.x * DT;

    for (int idx = tid; idx < P_ * LT; idx += 256) {
        const int p = idx >> 2;
        const int l = idx & 3;
        al[p][l] = alpha[((size_t)(b * L_ + l0 + l)) * P_ + p];
    }
    __syncthreads();

    const int d = d0 + tid * 2;
    float acc[LT][2] = {};
    for (int p = 0; p < P_; ++p) {
        const float2 x = *reinterpret_cast<const float2*>(x1 + ((size_t)(b * P_ + p)) * DIM1 + d);
        const float4 a4 = *reinterpret_cast<const float4*>(&al[p][0]);
        acc[0][0] = fmaf(a4.x, x.x, acc[0][0]);
        acc[0][1] = fmaf(a4.x, x.y, acc[0][1]);
        acc[1][0] = fmaf(a4.y, x.x, acc[1][0]);
        acc[1][1] = fmaf(a4.y, x.y, acc[1][1]);
        acc[2][0] = fmaf(a4.z, x.x, acc[2][0]);
        acc[2][1] = fmaf(a4.z, x.y, acc[2][1]);
        acc[3][0] = fmaf(a4.w, x.x, acc[3][0]);
        acc[3][1] = fmaf(a4.w, x.y, acc[3][1]);
    }
#pragma unroll
    for (int l = 0; l < LT; ++l) {
        float* op = out + ((size_t)(b * L_ + l0 + l)) * DIM1 + d;
        op[0] = acc[l][0];
        op[1] = acc[l][1];
    }
}

// ---------------------------------------------------------------- launch
extern "C" void kernel_launch(void* const* d_in, const int* in_sizes, int n_in,
                              void* d_out, int out_size, void* d_ws, size_t ws_size,
                              hipStream_t stream) {
    const float* x1 = (const float*)d_in[0];
    const float* x2 = (const float*)d_in[1];
    const float* W1 = (const float*)d_in[2];
    const float* W2 = (const float*)d_in[3];
    const float* Wh = (const float*)d_in[4];
    const float* bh = (const float*)d_in[5];
    const float* Wt = (const float*)d_in[6];
    const float* bt = (const float*)d_in[7];

    float* out       = (float*)d_out;
    float* label_out = out;                                  // B*L*DIM1
    float* alpha_out = out + (size_t)B_ * L_ * DIM1;         // B*L*P

    // workspace layout (ushort offsets); a2b aliases W1T (dead after a1 gemm)
    unsigned short* usw = (unsigned short*)d_ws;
    unsigned short* W1T = usw;                         // 1024*2048 = 2097152
    unsigned short* a2b = usw;                         // 640*1024  (aliases W1T)
    unsigned short* W2T = usw + 2097152;               // 1024*320  = 327680
    unsigned short* a1b = usw + 2424832;               // 1568*1024 = 1605632
    float* wv    = (float*)(usw + 4030464);            // 1024
    float* biasv = wv + ATT;                           // 2

    prep_w<<<ATT / 4 + 1, 256, 0, stream>>>(Wh, bh, Wt, bt, wv, biasv);
    prep_sum<<<1, 256, 0, stream>>>(wv, biasv);

    tcast<<<dim3(DIM1 / 32, 32), 256, 0, stream>>>(W1, W1T, DIM1, DIM1);
    tcast<<<dim3(320 / 32, 32), 256, 0, stream>>>(W2, W2T, DIM2, 320);

    gemm_bf16<DIM1, DIM1><<<dim3(16, 25), 256, 0, stream>>>(x1, W1T, a1b, B_ * P_);
    gemm_bf16<DIM2, 320><<<dim3(16, 10), 256, 0, stream>>>(x2, W2T, a2b, B_ * L_);

    score_softmax<<<B_ * L_, 256, 0, stream>>>(a1b, a2b, wv, biasv, alpha_out);

    label_kernel<<<dim3(DIM1 / DT, L_ / LT, B_), 256, 0, stream>>>(
        alpha_out, x1, label_out);
}

// Round 7
// 193.447 us; speedup vs baseline: 2.2945x; 1.0132x over previous
//
#include <hip/hip_runtime.h>
#include <math.h>

#define B_   8
#define P_   196
#define L_   80
#define DIM1 2048
#define DIM2 300
#define ATT  1024

typedef __attribute__((ext_vector_type(8))) short short8_t;
typedef __attribute__((ext_vector_type(4))) float f32x4_t;

__device__ inline unsigned short f2bf(float f) {
    unsigned int u = __float_as_uint(f);
    u += 0x7fff + ((u >> 16) & 1);          // RNE
    return (unsigned short)(u >> 16);
}
__device__ inline float bf2f(unsigned short h) {
    return __uint_as_float(((unsigned int)h) << 16);
}

// ---------------------------------------------------------------- prep: w = Wh@Wt, bias = bh.Wt + bt
__global__ __launch_bounds__(256) void prep_w(const float* __restrict__ Wh,
                                              const float* __restrict__ bh,
                                              const float* __restrict__ Wt,
                                              const float* __restrict__ btp,
                                              float* __restrict__ w,
                                              float* __restrict__ biasp) {
    const int tid  = threadIdx.x;
    const int lane = tid & 63;
    const int row  = blockIdx.x * 4 + (tid >> 6);
    const float* src = (row < ATT) ? (Wh + (size_t)row * ATT) : bh;
    if (row <= ATT) {
        float acc = 0.0f;
#pragma unroll
        for (int it = 0; it < ATT / 256; ++it) {
            const int i = it * 256 + lane * 4;
            const float4 a = *reinterpret_cast<const float4*>(src + i);
            const float4 b = *reinterpret_cast<const float4*>(Wt + i);
            acc = fmaf(a.x, b.x, acc);
            acc = fmaf(a.y, b.y, acc);
            acc = fmaf(a.z, b.z, acc);
            acc = fmaf(a.w, b.w, acc);
        }
#pragma unroll
        for (int o = 32; o >= 1; o >>= 1) acc += __shfl_xor(acc, o);
        if (lane == 0) {
            if (row < ATT) w[row] = acc;
            else           biasp[0] = acc + btp[0];
        }
    }
}

// bias2 = bias + sum(w)   (score = bias + sumw - 2*sum(w*r))
__global__ __launch_bounds__(256) void prep_sum(const float* __restrict__ w,
                                                float* __restrict__ biasp) {
    __shared__ float red[4];
    const int tid = threadIdx.x;
    float s = 0.f;
    for (int i = tid; i < ATT; i += 256) s += w[i];
#pragma unroll
    for (int o = 32; o >= 1; o >>= 1) s += __shfl_xor(s, o);
    if ((tid & 63) == 0) red[tid >> 6] = s;
    __syncthreads();
    if (tid == 0) biasp[1] = biasp[0] + red[0] + red[1] + red[2] + red[3];
}

// ---------------------------------------------------------------- transpose+cast: in[Ksrc][1024] f32 -> out[1024][Kpad] bf16 (zero-pad k)
__global__ __launch_bounds__(256) void tcast(const float* __restrict__ in,
                                             unsigned short* __restrict__ out,
                                             int Ksrc, int Kpad) {
    __shared__ unsigned short tile[32][34];
    const int tx = threadIdx.x & 31, ty = threadIdx.x >> 5;   // 32 x 8
    const int k0 = blockIdx.x * 32, n0 = blockIdx.y * 32;
#pragma unroll
    for (int i = 0; i < 4; ++i) {
        const int r = k0 + ty + i * 8;
        const float v = (r < Ksrc) ? in[(size_t)r * 1024 + n0 + tx] : 0.f;
        tile[ty + i * 8][tx] = f2bf(v);
    }
    __syncthreads();
#pragma unroll
    for (int i = 0; i < 4; ++i) {
        const int n = ty + i * 8;
        out[(size_t)(n0 + n) * Kpad + k0 + tx] = tile[tx][n];
    }
}

// ---------------------------------------------------------------- bf16 MFMA GEMM, pipelined
// C[M][1024](bf16) = A[M][KSRC](f32, cast on stage) @ Bt[1024][KPAD](bf16)^T.
// 64x64 tile, BK=64, 4 waves (32x32 each), 16x16x32 bf16 MFMA.
// Double-buffered LDS, ONE barrier per K-step; loads for t+1 issued under
// compute of t. LDS rows 128 B pitch, XOR swizzle byte^=((row&7)<<4).
template<int KSRC, int KPAD>
__global__ __launch_bounds__(256) void gemm_bf16(const float* __restrict__ Af,
                                                 const unsigned short* __restrict__ Bt,
                                                 unsigned short* __restrict__ C,
                                                 int M) {
    constexpr int NT = KPAD / 64;
    __shared__ __align__(16) char smem[32768];   // [buf][A 8K | B 8K]
    const int tid  = threadIdx.x;
    const int lane = tid & 63;
    const int wave = tid >> 6;
    const int wm = (wave >> 1) * 32;
    const int wn = (wave & 1) * 32;
    const int m0 = blockIdx.y * 64;
    const int n0 = blockIdx.x * 64;

    const int row = tid >> 2;            // 0..63 staging row
    const int kc  = (tid & 3) * 16;      // k element offset within BK
    const int swz = (row & 7) << 4;
    const int sb  = row * 128 + kc * 2;  // staging byte base (pre-XOR)
    const int gm  = m0 + row;

    float4   ra[4];                      // 16 f32 of A
    short8_t rb[2];                      // 16 bf16 of B

    auto LOAD = [&](int t) {
        const int k0 = t * 64;
        if (gm < M && k0 + 64 <= KSRC) {
            const float* ap = Af + (size_t)gm * KSRC + k0 + kc;
            ra[0] = *reinterpret_cast<const float4*>(ap);
            ra[1] = *reinterpret_cast<const float4*>(ap + 4);
            ra[2] = *reinterpret_cast<const float4*>(ap + 8);
            ra[3] = *reinterpret_cast<const float4*>(ap + 12);
        } else {
            float* rf = reinterpret_cast<float*>(ra);
#pragma unroll
            for (int j = 0; j < 16; ++j) {
                const int k = k0 + kc + j;
                rf[j] = (gm < M && k < KSRC) ? Af[(size_t)gm * KSRC + k] : 0.f;
            }
        }
        const unsigned short* bp = Bt + (size_t)(n0 + row) * KPAD + k0 + kc;
        rb[0] = *reinterpret_cast<const short8_t*>(bp);
        rb[1] = *reinterpret_cast<const short8_t*>(bp + 8);
    };

    auto WRITE = [&](int buf) {
        char* smA = smem + buf * 16384;
        char* smB = smA + 8192;
        const float* rf = reinterpret_cast<const float*>(ra);
        short8_t h0, h1;
#pragma unroll
        for (int j = 0; j < 8; ++j) h0[j] = (short)f2bf(rf[j]);
#pragma unroll
        for (int j = 0; j < 8; ++j) h1[j] = (short)f2bf(rf[8 + j]);
        *reinterpret_cast<short8_t*>(smA + ((sb)      ^ swz)) = h0;
        *reinterpret_cast<short8_t*>(smA + ((sb + 16) ^ swz)) = h1;
        *reinterpret_cast<short8_t*>(smB + ((sb)      ^ swz)) = rb[0];
        *reinterpret_cast<short8_t*>(smB + ((sb + 16) ^ swz)) = rb[1];
    };

    f32x4_t acc[2][2] = {};
    const int fr_col = (lane >> 4) << 4;   // frag k-group byte offset
    const int fl     = lane & 15;

    LOAD(0);
#pragma unroll 2
    for (int t = 0; t < NT; ++t) {
        const int buf = t & 1;
        WRITE(buf);                        // vmcnt drain for tile t happens here
        __syncthreads();
        if (t + 1 < NT) LOAD(t + 1);       // issue next tile, no wait
        const char* smA = smem + buf * 16384;
        const char* smB = smA + 8192;
#pragma unroll
        for (int kk = 0; kk < 2; ++kk) {
            short8_t af[2], bf[2];
#pragma unroll
            for (int i = 0; i < 2; ++i) {
                const int r = wm + i * 16 + fl;
                af[i] = *reinterpret_cast<const short8_t*>(
                    smA + ((r * 128 + kk * 64 + fr_col) ^ ((r & 7) << 4)));
            }
#pragma unroll
            for (int j = 0; j < 2; ++j) {
                const int r = wn + j * 16 + fl;
                bf[j] = *reinterpret_cast<const short8_t*>(
                    smB + ((r * 128 + kk * 64 + fr_col) ^ ((r & 7) << 4)));
            }
#pragma unroll
            for (int i = 0; i < 2; ++i)
#pragma unroll
                for (int j = 0; j < 2; ++j)
                    acc[i][j] = __builtin_amdgcn_mfma_f32_16x16x32_bf16(af[i], bf[j], acc[i][j], 0, 0, 0);
        }
        __syncthreads();
    }

    // epilogue: C/D layout col=lane&15, row=(lane>>4)*4+q
#pragma unroll
    for (int i = 0; i < 2; ++i) {
        const int gmb = m0 + wm + i * 16 + ((lane >> 4) << 2);
#pragma unroll
        for (int j = 0; j < 2; ++j) {
            const int gn = n0 + wn + j * 16 + fl;
#pragma unroll
            for (int q = 0; q < 4; ++q) {
                const int gmq = gmb + q;
                if (gmq < M) C[(size_t)gmq * 1024 + gn] = f2bf(acc[i][j][q]);
            }
        }
    }
}

// ---------------------------------------------------------------- fused score + softmax (bf16 a1/a2)
// score = bias2 - 2 * sum_a w[a] * rcp(exp2(C * a1 * a2) + 1),  C = 2*log2(e)
// Each wave processes FOUR p-rows concurrently (196 = 49 groups of 4,
// wave-strided): the aw[] LDS read is shared across the 4 rows and the 4
// independent exp2->rcp->fma chains cover trans-pipe latency.
__global__ __launch_bounds__(256) void score_softmax(const unsigned short* __restrict__ a1b,
                                                     const unsigned short* __restrict__ a2b,
                                                     const float* __restrict__ w,
                                                     const float* __restrict__ biasp,
                                                     float* __restrict__ alpha) {
    __shared__ float2 aw[ATT];
    __shared__ float sc[P_];
    __shared__ float red[4];
    const int tid  = threadIdx.x;
    const int lane = tid & 63;
    const int wave = tid >> 6;
    const int b = blockIdx.x & 7;      // batch -> XCD (L2 residency of a1 slice)
    const int l = blockIdx.x >> 3;
    const float bias2 = biasp[1];

    const unsigned short* a2p = a2b + (size_t)(b * L_ + l) * ATT;
    for (int i = tid; i < ATT; i += 256) {
        const float a2v = bf2f(a2p[i]);
        const int li = i & 511;
        const int phi = (i & ~511) | (((li & 7) << 6) + (li >> 3));
        aw[phi] = make_float2(a2v * 2.885390082f, w[i]);   // 2*log2(e)
    }
    __syncthreads();

    for (int p0 = wave * 4; p0 < P_; p0 += 16) {
        const unsigned short* a1p = a1b + (size_t)(b * P_ + p0) * ATT;
        float acc[4] = {0.f, 0.f, 0.f, 0.f};
#pragma unroll
        for (int it = 0; it < 2; ++it) {
            short8_t v[4];
#pragma unroll
            for (int q = 0; q < 4; ++q)
                v[q] = *reinterpret_cast<const short8_t*>(a1p + q * ATT + it * 512 + lane * 8);
#pragma unroll
            for (int j = 0; j < 8; ++j) {
                const float2 c = aw[it * 512 + j * 64 + lane];
#pragma unroll
                for (int q = 0; q < 4; ++q) {
                    const float f = bf2f((unsigned short)v[q][j]);
                    const float e = __builtin_amdgcn_exp2f(f * c.x);
                    const float r = __builtin_amdgcn_rcpf(e + 1.0f);
                    acc[q] = fmaf(c.y, r, acc[q]);
                }
            }
        }
#pragma unroll
        for (int o = 32; o >= 1; o >>= 1) {
#pragma unroll
            for (int q = 0; q < 4; ++q) acc[q] += __shfl_xor(acc[q], o);
        }
        if (lane < 4) sc[p0 + lane] = bias2 - 2.0f * acc[lane];
    }
    __syncthreads();

    const float v = (tid < P_) ? sc[tid] : -INFINITY;
    float m = v;
#pragma unroll
    for (int o = 32; o >= 1; o >>= 1) m = fmaxf(m, __shfl_xor(m, o));
    if (lane == 0) red[wave] = m;
    __syncthreads();
    m = fmaxf(fmaxf(red[0], red[1]), fmaxf(red[2], red[3]));

    const float e = (tid < P_) ? __expf(v - m) : 0.0f;
    float s = e;
#pragma unroll
    for (int o = 32; o >= 1; o >>= 1) s += __shfl_xor(s, o);
    __syncthreads();
    if (lane == 0) red[wave] = s;
    __syncthreads();
    s = red[0] + red[1] + red[2] + red[3];

    if (tid < P_) alpha[(size_t)(b * L_ + l) * P_ + tid] = e / s;
}

// ---------------------------------------------------------------- label_repr = alpha @ x1 (per batch)
#define LT 4
#define DT 512
__global__ __launch_bounds__(256) void label_kernel(const float* __restrict__ alpha,
                                                    const float* __restrict__ x1,
                                                    float* __restrict__ out) {
    __shared__ float al[P_][LT];
    const int tid = threadIdx.x;
    const int b  = blockIdx.z;
    const int l0 = blockIdx.y * LT;
    const int d0 = blockIdx.x * DT;

    for (int idx = tid; idx < P_ * LT; idx += 256) {
        const int p = idx >> 2;
        const int l = idx & 3;
        al[p][l] = alpha[((size_t)(b * L_ + l0 + l)) * P_ + p];
    }
    __syncthreads();

    const int d = d0 + tid * 2;
    float acc[LT][2] = {};
    for (int p = 0; p < P_; ++p) {
        const float2 x = *reinterpret_cast<const float2*>(x1 + ((size_t)(b * P_ + p)) * DIM1 + d);
        const float4 a4 = *reinterpret_cast<const float4*>(&al[p][0]);
        acc[0][0] = fmaf(a4.x, x.x, acc[0][0]);
        acc[0][1] = fmaf(a4.x, x.y, acc[0][1]);
        acc[1][0] = fmaf(a4.y, x.x, acc[1][0]);
        acc[1][1] = fmaf(a4.y, x.y, acc[1][1]);
        acc[2][0] = fmaf(a4.z, x.x, acc[2][0]);
        acc[2][1] = fmaf(a4.z, x.y, acc[2][1]);
        acc[3][0] = fmaf(a4.w, x.x, acc[3][0]);
        acc[3][1] = fmaf(a4.w, x.y, acc[3][1]);
    }
#pragma unroll
    for (int l = 0; l < LT; ++l) {
        float* op = out + ((size_t)(b * L_ + l0 + l)) * DIM1 + d;
        op[0] = acc[l][0];
        op[1] = acc[l][1];
    }
}

// ---------------------------------------------------------------- launch
extern "C" void kernel_launch(void* const* d_in, const int* in_sizes, int n_in,
                              void* d_out, int out_size, void* d_ws, size_t ws_size,
                              hipStream_t stream) {
    const float* x1 = (const float*)d_in[0];
    const float* x2 = (const float*)d_in[1];
    const float* W1 = (const float*)d_in[2];
    const float* W2 = (const float*)d_in[3];
    const float* Wh = (const float*)d_in[4];
    const float* bh = (const float*)d_in[5];
    const float* Wt = (const float*)d_in[6];
    const float* bt = (const float*)d_in[7];

    float* out       = (float*)d_out;
    float* label_out = out;                                  // B*L*DIM1
    float* alpha_out = out + (size_t)B_ * L_ * DIM1;         // B*L*P

    // workspace layout (ushort offsets); a2b aliases W1T (dead after a1 gemm)
    unsigned short* usw = (unsigned short*)d_ws;
    unsigned short* W1T = usw;                         // 1024*2048 = 2097152
    unsigned short* a2b = usw;                         // 640*1024  (aliases W1T)
    unsigned short* W2T = usw + 2097152;               // 1024*320  = 327680
    unsigned short* a1b = usw + 2424832;               // 1568*1024 = 1605632
    float* wv    = (float*)(usw + 4030464);            // 1024
    float* biasv = wv + ATT;                           // 2

    prep_w<<<ATT / 4 + 1, 256, 0, stream>>>(Wh, bh, Wt, bt, wv, biasv);
    prep_sum<<<1, 256, 0, stream>>>(wv, biasv);

    tcast<<<dim3(DIM1 / 32, 32), 256, 0, stream>>>(W1, W1T, DIM1, DIM1);
    tcast<<<dim3(320 / 32, 32), 256, 0, stream>>>(W2, W2T, DIM2, 320);

    gemm_bf16<DIM1, DIM1><<<dim3(16, 25), 256, 0, stream>>>(x1, W1T, a1b, B_ * P_);
    gemm_bf16<DIM2, 320><<<dim3(16, 10), 256, 0, stream>>>(x2, W2T, a2b, B_ * L_);

    score_softmax<<<B_ * L_, 256, 0, stream>>>(a1b, a2b, wv, biasv, alpha_out);

    label_kernel<<<dim3(DIM1 / DT, L_ / LT, B_), 256, 0, stream>>>(
        alpha_out, x1, label_out);
}

// Round 8
// 192.166 us; speedup vs baseline: 2.3098x; 1.0067x over previous
//
#include <hip/hip_runtime.h>
#include <math.h>

#define B_   8
#define P_   196
#define L_   80
#define DIM1 2048
#define DIM2 300
#define ATT  1024

typedef __attribute__((ext_vector_type(8))) short short8_t;
typedef __attribute__((ext_vector_type(4))) float f32x4_t;

__device__ inline unsigned short f2bf(float f) {
    unsigned int u = __float_as_uint(f);
    u += 0x7fff + ((u >> 16) & 1);          // RNE
    return (unsigned short)(u >> 16);
}
__device__ inline float bf2f(unsigned short h) {
    return __uint_as_float(((unsigned int)h) << 16);
}

// ---------------------------------------------------------------- prep: w = Wh@Wt, bias = bh.Wt + bt
__global__ __launch_bounds__(256) void prep_w(const float* __restrict__ Wh,
                                              const float* __restrict__ bh,
                                              const float* __restrict__ Wt,
                                              const float* __restrict__ btp,
                                              float* __restrict__ w,
                                              float* __restrict__ biasp) {
    const int tid  = threadIdx.x;
    const int lane = tid & 63;
    const int row  = blockIdx.x * 4 + (tid >> 6);
    const float* src = (row < ATT) ? (Wh + (size_t)row * ATT) : bh;
    if (row <= ATT) {
        float acc = 0.0f;
#pragma unroll
        for (int it = 0; it < ATT / 256; ++it) {
            const int i = it * 256 + lane * 4;
            const float4 a = *reinterpret_cast<const float4*>(src + i);
            const float4 b = *reinterpret_cast<const float4*>(Wt + i);
            acc = fmaf(a.x, b.x, acc);
            acc = fmaf(a.y, b.y, acc);
            acc = fmaf(a.z, b.z, acc);
            acc = fmaf(a.w, b.w, acc);
        }
#pragma unroll
        for (int o = 32; o >= 1; o >>= 1) acc += __shfl_xor(acc, o);
        if (lane == 0) {
            if (row < ATT) w[row] = acc;
            else           biasp[0] = acc + btp[0];
        }
    }
}

// bias2 = bias + sum(w)   (score = bias + sumw - 2*sum(w*r))
__global__ __launch_bounds__(256) void prep_sum(const float* __restrict__ w,
                                                float* __restrict__ biasp) {
    __shared__ float red[4];
    const int tid = threadIdx.x;
    float s = 0.f;
    for (int i = tid; i < ATT; i += 256) s += w[i];
#pragma unroll
    for (int o = 32; o >= 1; o >>= 1) s += __shfl_xor(s, o);
    if ((tid & 63) == 0) red[tid >> 6] = s;
    __syncthreads();
    if (tid == 0) biasp[1] = biasp[0] + red[0] + red[1] + red[2] + red[3];
}

// ---------------------------------------------------------------- transpose+cast: in[Ksrc][1024] f32 -> out[1024][Kpad] bf16 (zero-pad k)
__global__ __launch_bounds__(256) void tcast(const float* __restrict__ in,
                                             unsigned short* __restrict__ out,
                                             int Ksrc, int Kpad) {
    __shared__ unsigned short tile[32][34];
    const int tx = threadIdx.x & 31, ty = threadIdx.x >> 5;   // 32 x 8
    const int k0 = blockIdx.x * 32, n0 = blockIdx.y * 32;
#pragma unroll
    for (int i = 0; i < 4; ++i) {
        const int r = k0 + ty + i * 8;
        const float v = (r < Ksrc) ? in[(size_t)r * 1024 + n0 + tx] : 0.f;
        tile[ty + i * 8][tx] = f2bf(v);
    }
    __syncthreads();
#pragma unroll
    for (int i = 0; i < 4; ++i) {
        const int n = ty + i * 8;
        out[(size_t)(n0 + n) * Kpad + k0 + tx] = tile[tx][n];
    }
}

// ---------------------------------------------------------------- bf16 MFMA GEMM, pipelined
// C[M][1024](bf16) = A[M][KSRC](f32, cast on stage) @ Bt[1024][KPAD](bf16)^T.
// 64x64 tile, BK=64, 4 waves (32x32 each), 16x16x32 bf16 MFMA.
// Double-buffered LDS, ONE barrier per K-step; loads for t+1 issued under
// compute of t. LDS rows 128 B pitch, XOR swizzle byte^=((row&7)<<4).
template<int KSRC, int KPAD>
__global__ __launch_bounds__(256) void gemm_bf16(const float* __restrict__ Af,
                                                 const unsigned short* __restrict__ Bt,
                                                 unsigned short* __restrict__ C,
                                                 int M) {
    constexpr int NT = KPAD / 64;
    __shared__ __align__(16) char smem[32768];   // [buf][A 8K | B 8K]
    const int tid  = threadIdx.x;
    const int lane = tid & 63;
    const int wave = tid >> 6;
    const int wm = (wave >> 1) * 32;
    const int wn = (wave & 1) * 32;
    const int m0 = blockIdx.y * 64;
    const int n0 = blockIdx.x * 64;

    const int row = tid >> 2;            // 0..63 staging row
    const int kc  = (tid & 3) * 16;      // k element offset within BK
    const int swz = (row & 7) << 4;
    const int sb  = row * 128 + kc * 2;  // staging byte base (pre-XOR)
    const int gm  = m0 + row;

    float4   ra[4];                      // 16 f32 of A
    short8_t rb[2];                      // 16 bf16 of B

    auto LOAD = [&](int t) {
        const int k0 = t * 64;
        if (gm < M && k0 + 64 <= KSRC) {
            const float* ap = Af + (size_t)gm * KSRC + k0 + kc;
            ra[0] = *reinterpret_cast<const float4*>(ap);
            ra[1] = *reinterpret_cast<const float4*>(ap + 4);
            ra[2] = *reinterpret_cast<const float4*>(ap + 8);
            ra[3] = *reinterpret_cast<const float4*>(ap + 12);
        } else {
            float* rf = reinterpret_cast<float*>(ra);
#pragma unroll
            for (int j = 0; j < 16; ++j) {
                const int k = k0 + kc + j;
                rf[j] = (gm < M && k < KSRC) ? Af[(size_t)gm * KSRC + k] : 0.f;
            }
        }
        const unsigned short* bp = Bt + (size_t)(n0 + row) * KPAD + k0 + kc;
        rb[0] = *reinterpret_cast<const short8_t*>(bp);
        rb[1] = *reinterpret_cast<const short8_t*>(bp + 8);
    };

    auto WRITE = [&](int buf) {
        char* smA = smem + buf * 16384;
        char* smB = smA + 8192;
        const float* rf = reinterpret_cast<const float*>(ra);
        short8_t h0, h1;
#pragma unroll
        for (int j = 0; j < 8; ++j) h0[j] = (short)f2bf(rf[j]);
#pragma unroll
        for (int j = 0; j < 8; ++j) h1[j] = (short)f2bf(rf[8 + j]);
        *reinterpret_cast<short8_t*>(smA + ((sb)      ^ swz)) = h0;
        *reinterpret_cast<short8_t*>(smA + ((sb + 16) ^ swz)) = h1;
        *reinterpret_cast<short8_t*>(smB + ((sb)      ^ swz)) = rb[0];
        *reinterpret_cast<short8_t*>(smB + ((sb + 16) ^ swz)) = rb[1];
    };

    f32x4_t acc[2][2] = {};
    const int fr_col = (lane >> 4) << 4;   // frag k-group byte offset
    const int fl     = lane & 15;

    LOAD(0);
#pragma unroll 2
    for (int t = 0; t < NT; ++t) {
        const int buf = t & 1;
        WRITE(buf);                        // vmcnt drain for tile t happens here
        __syncthreads();
        if (t + 1 < NT) LOAD(t + 1);       // issue next tile, no wait
        const char* smA = smem + buf * 16384;
        const char* smB = smA + 8192;
#pragma unroll
        for (int kk = 0; kk < 2; ++kk) {
            short8_t af[2], bf[2];
#pragma unroll
            for (int i = 0; i < 2; ++i) {
                const int r = wm + i * 16 + fl;
                af[i] = *reinterpret_cast<const short8_t*>(
                    smA + ((r * 128 + kk * 64 + fr_col) ^ ((r & 7) << 4)));
            }
#pragma unroll
            for (int j = 0; j < 2; ++j) {
                const int r = wn + j * 16 + fl;
                bf[j] = *reinterpret_cast<const short8_t*>(
                    smB + ((r * 128 + kk * 64 + fr_col) ^ ((r & 7) << 4)));
            }
#pragma unroll
            for (int i = 0; i < 2; ++i)
#pragma unroll
                for (int j = 0; j < 2; ++j)
                    acc[i][j] = __builtin_amdgcn_mfma_f32_16x16x32_bf16(af[i], bf[j], acc[i][j], 0, 0, 0);
        }
        __syncthreads();
    }

    // epilogue: C/D layout col=lane&15, row=(lane>>4)*4+q
#pragma unroll
    for (int i = 0; i < 2; ++i) {
        const int gmb = m0 + wm + i * 16 + ((lane >> 4) << 2);
#pragma unroll
        for (int j = 0; j < 2; ++j) {
            const int gn = n0 + wn + j * 16 + fl;
#pragma unroll
            for (int q = 0; q < 4; ++q) {
                const int gmq = gmb + q;
                if (gmq < M) C[(size_t)gmq * 1024 + gn] = f2bf(acc[i][j][q]);
            }
        }
    }
}

// ---------------------------------------------------------------- score (p-split x4 for occupancy)
// score = bias2 - 2 * sum_a w[a] * rcp(exp2(C * a1 * a2) + 1),  C = 2*log2(e)
// Grid 2560 = (b in lowbits -> XCD) x l x quarter; each block computes 49
// p-rows. 4 rows per wave concurrently: aw[] LDS read amortized x4, 4
// independent trans chains. Raw scores to workspace; softmax_k finishes.
__global__ __launch_bounds__(256) void score_part(const unsigned short* __restrict__ a1b,
                                                  const unsigned short* __restrict__ a2b,
                                                  const float* __restrict__ w,
                                                  const float* __restrict__ biasp,
                                                  float* __restrict__ scb) {
    __shared__ float2 aw[ATT];
    const int tid  = threadIdx.x;
    const int lane = tid & 63;
    const int wave = tid >> 6;
    const int b    = blockIdx.x & 7;      // batch -> XCD (L2 residency of a1 slice)
    const int rest = blockIdx.x >> 3;     // 0..319
    const int l    = rest >> 2;
    const int qtr  = rest & 3;
    const float bias2 = biasp[1];

    const unsigned short* a2p = a2b + (size_t)(b * L_ + l) * ATT;
    for (int i = tid; i < ATT; i += 256) {
        const float a2v = bf2f(a2p[i]);
        const int li = i & 511;
        const int phi = (i & ~511) | (((li & 7) << 6) + (li >> 3));
        aw[phi] = make_float2(a2v * 2.885390082f, w[i]);   // 2*log2(e)
    }
    __syncthreads();

    const int base = qtr * 49;
    float* scp = scb + (size_t)(b * L_ + l) * P_;

    for (int g = wave; g < 13; g += 4) {          // 13 groups of 4 rows (last partial)
        const int p0 = base + g * 4;
        int r[4];
#pragma unroll
        for (int q = 0; q < 4; ++q) r[q] = min(p0 + q, P_ - 1);
        float acc[4] = {0.f, 0.f, 0.f, 0.f};
#pragma unroll
        for (int it = 0; it < 2; ++it) {
            short8_t v[4];
#pragma unroll
            for (int q = 0; q < 4; ++q)
                v[q] = *reinterpret_cast<const short8_t*>(
                    a1b + (size_t)(b * P_ + r[q]) * ATT + it * 512 + lane * 8);
#pragma unroll
            for (int j = 0; j < 8; ++j) {
                const float2 c = aw[it * 512 + j * 64 + lane];
#pragma unroll
                for (int q = 0; q < 4; ++q) {
                    const float f = bf2f((unsigned short)v[q][j]);
                    const float e = __builtin_amdgcn_exp2f(f * c.x);
                    const float rr = __builtin_amdgcn_rcpf(e + 1.0f);
                    acc[q] = fmaf(c.y, rr, acc[q]);
                }
            }
        }
#pragma unroll
        for (int o = 32; o >= 1; o >>= 1) {
#pragma unroll
            for (int q = 0; q < 4; ++q) acc[q] += __shfl_xor(acc[q], o);
        }
        if (lane < 4) {
            const int p = p0 + lane;
            if (p < base + 49) scp[p] = bias2 - 2.0f * acc[lane];
        }
    }
}

// ---------------------------------------------------------------- softmax over p (one wave per (b,l) row)
__global__ __launch_bounds__(256) void softmax_k(const float* __restrict__ scb,
                                                 float* __restrict__ alpha) {
    const int tid  = threadIdx.x;
    const int lane = tid & 63;
    const int wave = tid >> 6;
    const int row  = blockIdx.x * 4 + wave;       // 0..639
    const float* sp = scb + (size_t)row * P_;

    float v[4];
#pragma unroll
    for (int k = 0; k < 4; ++k) {
        const int p = lane + k * 64;
        v[k] = (p < P_) ? sp[p] : -INFINITY;
    }
    float m = fmaxf(fmaxf(v[0], v[1]), fmaxf(v[2], v[3]));
#pragma unroll
    for (int o = 32; o >= 1; o >>= 1) m = fmaxf(m, __shfl_xor(m, o));

    float e[4];
    float s = 0.f;
#pragma unroll
    for (int k = 0; k < 4; ++k) {
        const int p = lane + k * 64;
        e[k] = (p < P_) ? __expf(v[k] - m) : 0.f;
        s += e[k];
    }
#pragma unroll
    for (int o = 32; o >= 1; o >>= 1) s += __shfl_xor(s, o);
    const float inv = 1.0f / s;

    float* ap = alpha + (size_t)row * P_;
#pragma unroll
    for (int k = 0; k < 4; ++k) {
        const int p = lane + k * 64;
        if (p < P_) ap[p] = e[k] * inv;
    }
}

// ---------------------------------------------------------------- label_repr = alpha @ x1 (per batch)
#define LT 4
#define DT 512
__global__ __launch_bounds__(256) void label_kernel(const float* __restrict__ alpha,
                                                    const float* __restrict__ x1,
                                                    float* __restrict__ out) {
    __shared__ float al[P_][LT];
    const int tid = threadIdx.x;
    const int b  = blockIdx.z;
    const int l0 = blockIdx.y * LT;
    const int d0 = blockIdx.x * DT;

    for (int idx = tid; idx < P_ * LT; idx += 256) {
        const int p = idx >> 2;
        const int l = idx & 3;
        al[p][l] = alpha[((size_t)(b * L_ + l0 + l)) * P_ + p];
    }
    __syncthreads();

    const int d = d0 + tid * 2;
    float acc[LT][2] = {};
    for (int p = 0; p < P_; ++p) {
        const float2 x = *reinterpret_cast<const float2*>(x1 + ((size_t)(b * P_ + p)) * DIM1 + d);
        const float4 a4 = *reinterpret_cast<const float4*>(&al[p][0]);
        acc[0][0] = fmaf(a4.x, x.x, acc[0][0]);
        acc[0][1] = fmaf(a4.x, x.y, acc[0][1]);
        acc[1][0] = fmaf(a4.y, x.x, acc[1][0]);
        acc[1][1] = fmaf(a4.y, x.y, acc[1][1]);
        acc[2][0] = fmaf(a4.z, x.x, acc[2][0]);
        acc[2][1] = fmaf(a4.z, x.y, acc[2][1]);
        acc[3][0] = fmaf(a4.w, x.x, acc[3][0]);
        acc[3][1] = fmaf(a4.w, x.y, acc[3][1]);
    }
#pragma unroll
    for (int l = 0; l < LT; ++l) {
        float* op = out + ((size_t)(b * L_ + l0 + l)) * DIM1 + d;
        op[0] = acc[l][0];
        op[1] = acc[l][1];
    }
}

// ---------------------------------------------------------------- launch
extern "C" void kernel_launch(void* const* d_in, const int* in_sizes, int n_in,
                              void* d_out, int out_size, void* d_ws, size_t ws_size,
                              hipStream_t stream) {
    const float* x1 = (const float*)d_in[0];
    const float* x2 = (const float*)d_in[1];
    const float* W1 = (const float*)d_in[2];
    const float* W2 = (const float*)d_in[3];
    const float* Wh = (const float*)d_in[4];
    const float* bh = (const float*)d_in[5];
    const float* Wt = (const float*)d_in[6];
    const float* bt = (const float*)d_in[7];

    float* out       = (float*)d_out;
    float* label_out = out;                                  // B*L*DIM1
    float* alpha_out = out + (size_t)B_ * L_ * DIM1;         // B*L*P

    // workspace layout (ushort offsets); a2b aliases W1T (dead after a1 gemm)
    unsigned short* usw = (unsigned short*)d_ws;
    unsigned short* W1T = usw;                         // 1024*2048 = 2097152
    unsigned short* a2b = usw;                         // 640*1024  (aliases W1T)
    unsigned short* W2T = usw + 2097152;               // 1024*320  = 327680
    unsigned short* a1b = usw + 2424832;               // 1568*1024 = 1605632
    float* wv    = (float*)(usw + 4030464);            // 1024
    float* biasv = wv + ATT;                           // 2
    float* scb   = wv + 1028;                          // 640*196 raw scores

    prep_w<<<ATT / 4 + 1, 256, 0, stream>>>(Wh, bh, Wt, bt, wv, biasv);
    prep_sum<<<1, 256, 0, stream>>>(wv, biasv);

    tcast<<<dim3(DIM1 / 32, 32), 256, 0, stream>>>(W1, W1T, DIM1, DIM1);
    tcast<<<dim3(320 / 32, 32), 256, 0, stream>>>(W2, W2T, DIM2, 320);

    gemm_bf16<DIM1, DIM1><<<dim3(16, 25), 256, 0, stream>>>(x1, W1T, a1b, B_ * P_);
    gemm_bf16<DIM2, 320><<<dim3(16, 10), 256, 0, stream>>>(x2, W2T, a2b, B_ * L_);

    score_part<<<B_ * L_ * 4, 256, 0, stream>>>(a1b, a2b, wv, biasv, scb);
    softmax_k<<<B_ * L_ / 4, 256, 0, stream>>>(scb, alpha_out);

    label_kernel<<<dim3(DIM1 / DT, L_ / LT, B_), 256, 0, stream>>>(
        alpha_out, x1, label_out);
}